// Round 1
// baseline (33386.844 us; speedup 1.0000x reference)
//
#include <hip/hip_runtime.h>

// ---------------------------------------------------------------------------
// BiLSTM + CRF loss, MI355X.
// Structure: persistent LSTM kernel (256 WGs; group barrier per time step;
// weights register-resident as MFMA bf16 A-fragments), then CRF scan kernel.
// ---------------------------------------------------------------------------

constexpr int B_ = 32, T_ = 2048, D_ = 256, H_ = 256, K_ = 8;
constexpr int GB_ = 16;   // batches per group
constexpr int WJ_ = 64;   // workgroups per (dir, group)  -> 16 gate rows each

typedef __bf16 v8bf __attribute__((ext_vector_type(8)));
typedef float  v4f  __attribute__((ext_vector_type(4)));

// ws layout:
//   [0,       65536)  hex: h exchange [dir][group][parity][batch16][256] bf16
//   [65536,   66048)  barriers: 4 groups x 128B {cnt, gen}
//   [1MB,     3MB)    emisF  [B][T][K] f32
//   [3MB,     5MB)    emisB  [B][T][K] f32
__device__ __forceinline__ size_t hex_off(int d, int g, int par, int n, int m) {
  return ((((size_t)d * 2 + g) * 2 + par) * GB_ + n) * 256 + m;
}

__device__ __forceinline__ float sigm(float x)   { return 1.f / (1.f + __expf(-x)); }
__device__ __forceinline__ float tanh_f(float x) { float e = __expf(2.f * x); return 1.f - 2.f / (e + 1.f); }

__global__ void init_ws(int* p) {
  // zero hex (65536 B) + barriers (512 B) = 16512 ints
  for (int i = blockIdx.x * 256 + threadIdx.x; i < 16512; i += 32 * 256) p[i] = 0;
}

__global__ __launch_bounds__(256) void lstm_pass(
    const float* __restrict__ sent, const int* __restrict__ lengths,
    const float* __restrict__ w_ih_f, const float* __restrict__ w_hh_f,
    const float* __restrict__ b_ih_f, const float* __restrict__ b_hh_f,
    const float* __restrict__ w_ih_b, const float* __restrict__ w_hh_b,
    const float* __restrict__ b_ih_b, const float* __restrict__ b_hh_b,
    const float* __restrict__ w_tag,
    __bf16* hex, int* bars, float* emisF, float* emisB)
{
  const int blk  = blockIdx.x;
  const int d    = blk >> 7;          // direction
  const int g    = (blk >> 6) & 1;    // batch group
  const int j    = blk & 63;          // row-slice: owns h-elems [4j,4j+4)
  const int tid  = threadIdx.x;
  const int lane = tid & 63;
  const int w    = tid >> 6;          // wave id, owns k in [128w,128w+128)
  const int fm   = lane & 15;         // MFMA m/n index
  const int quad = lane >> 4;

  const float* w_ih = d ? w_ih_b : w_ih_f;
  const float* w_hh = d ? w_hh_b : w_hh_f;
  const float* b_ih = d ? b_ih_b : b_ih_f;
  const float* b_hh = d ? b_hh_b : b_hh_f;

  __shared__ float part[4][64][4];   // per-wave partial C tiles
  __shared__ float glds[16][16];     // reduced gates [rr][n]
  __shared__ float clds[4][16];      // cell state  [mm][n]
  __shared__ float biaslds[16];
  __shared__ float wtaglds[2][256];  // this WG's 2 w_tag rows (dir half)
  __shared__ int   lenlds[16];

  if (tid < 16) lenlds[tid] = lengths[g * GB_ + tid];
  if (tid < 16) {
    int mm = tid >> 2, q = tid & 3;
    int gr = q * 256 + (j * 4 + mm);
    biaslds[tid] = b_ih[gr] + b_hh[gr];
  }
  const int bb    = j >> 2;           // emis duty: local batch
  const int kpair = (j & 3) * 2;      // emis duty: tag pair
  for (int idx = tid; idx < 512; idx += 256) {
    int kk = idx >> 8, e = idx & 255;
    wtaglds[kk][e] = w_tag[(kpair + kk) * 512 + d * 256 + e];
  }
  if (tid < 64) clds[tid >> 4][tid & 15] = 0.f;
  __syncthreads();

  int Lmax = 0;
  #pragma unroll
  for (int i = 0; i < 16; ++i) Lmax = max(Lmax, lenlds[i]);

  // --- A-fragments (weights) in registers, bf16. rr = fm.
  // gate row gr = q*256 + (4j+mm), with rr = 4*mm + q  (mm = rr>>2, q = rr&3)
  const int rr = fm;
  const int gr = (rr & 3) * 256 + (j * 4 + (rr >> 2));
  v8bf afrag[4];
  #pragma unroll
  for (int ii = 0; ii < 4; ++ii) {
    int kb = (ii < 2) ? (64 * w + 32 * ii) : (256 + 64 * w + 32 * (ii - 2));
    int c0 = kb + quad * 8;
    const float* src = (c0 < 256) ? (w_ih + (size_t)gr * 256 + c0)
                                  : (w_hh + (size_t)gr * 256 + (c0 - 256));
    #pragma unroll
    for (int e = 0; e < 8; ++e) afrag[ii][e] = (__bf16)src[e];
  }

  const int nb  = fm;                 // B-fragment batch (lane&15)
  const int gbn = g * GB_ + nb;
  const int Ln  = lenlds[nb];
  const float* sentb = sent + (size_t)gbn * T_ * D_;

  int* cntp = bars + (d * 2 + g) * 32;
  int* genp = cntp + 1;

  auto wait_gen = [&](int target) {
    int spins = 0;
    while (__hip_atomic_load(genp, __ATOMIC_RELAXED, __HIP_MEMORY_SCOPE_AGENT) < target) {
      __builtin_amdgcn_s_sleep(1);
      if (++spins > (1 << 22)) break;   // safety valve: corrupt rather than hang
    }
    __builtin_amdgcn_fence(__ATOMIC_ACQUIRE, "agent");
  };

  auto do_emis = [&](int s) {           // emission for step s, wave 0 only
    if (w == 0 && s >= 0) {
      int Lb = lenlds[bb];
      if (s < Lb) {
        int kk = lane >> 5, eb = (lane & 31) * 8;
        v8bf hv = *(const v8bf*)(hex + hex_off(d, g, s & 1, bb, eb));
        float p = 0.f;
        #pragma unroll
        for (int e = 0; e < 8; ++e) p += (float)hv[e] * wtaglds[kk][eb + e];
        p += __shfl_xor(p, 1);  p += __shfl_xor(p, 2);  p += __shfl_xor(p, 4);
        p += __shfl_xor(p, 8);  p += __shfl_xor(p, 16);
        if ((lane & 31) == 0) {
          int pos = d ? (Lb - 1 - s) : s;
          float* dst = d ? emisB : emisF;
          dst[((size_t)(g * GB_ + bb) * T_ + pos) * K_ + kpair + kk] = p;
        }
      }
    }
  };

  for (int t = 0; t < Lmax; ++t) {
    // phase 1: x-part MFMAs (independent of barrier -> overlap the wait)
    int tx = (d == 0) ? t : max(Ln - 1 - t, 0);   // clamp keeps inactive lanes in-bounds
    const float* xrow = sentb + (size_t)tx * D_;
    v4f acc = {0.f, 0.f, 0.f, 0.f};
    #pragma unroll
    for (int ii = 0; ii < 2; ++ii) {
      int c0 = 64 * w + 32 * ii + quad * 8;
      float4 a = *(const float4*)(xrow + c0);
      float4 b2 = *(const float4*)(xrow + c0 + 4);
      v8bf bf;
      bf[0] = (__bf16)a.x;  bf[1] = (__bf16)a.y;  bf[2] = (__bf16)a.z;  bf[3] = (__bf16)a.w;
      bf[4] = (__bf16)b2.x; bf[5] = (__bf16)b2.y; bf[6] = (__bf16)b2.z; bf[7] = (__bf16)b2.w;
      acc = __builtin_amdgcn_mfma_f32_16x16x32_bf16(afrag[ii], bf, acc, 0, 0, 0);
    }
    // phase 2: wait for h_{t-1}
    wait_gen(t);
    // phase 3: emission for step t-1 (wave 0), h-part MFMAs (all waves)
    do_emis(t - 1);
    #pragma unroll
    for (int ii = 0; ii < 2; ++ii) {
      int m0 = 64 * w + 32 * ii + quad * 8;
      v8bf hb = *(const v8bf*)(hex + hex_off(d, g, (t + 1) & 1, nb, m0));
      acc = __builtin_amdgcn_mfma_f32_16x16x32_bf16(afrag[2 + ii], hb, acc, 0, 0, 0);
    }
    // phase 4: cross-wave k-reduction via LDS
    *(v4f*)&part[w][lane][0] = acc;
    __syncthreads();
    {
      int r2 = tid >> 4, n2 = tid & 15;
      int lq = (r2 >> 2) * 16 + n2, rg = r2 & 3;
      glds[r2][n2] = part[0][lq][rg] + part[1][lq][rg] +
                     part[2][lq][rg] + part[3][lq][rg] + biaslds[r2];
    }
    __syncthreads();
    // phase 6: LSTM cell update + publish h slice
    if (tid < 64) {
      int n2 = tid & 15, mm = tid >> 4;
      if (t < lenlds[n2]) {
        float gi = glds[4 * mm + 0][n2], gf = glds[4 * mm + 1][n2];
        float gg = glds[4 * mm + 2][n2], go = glds[4 * mm + 3][n2];
        float c = sigm(gf) * clds[mm][n2] + sigm(gi) * tanh_f(gg);
        clds[mm][n2] = c;
        float h = sigm(go) * tanh_f(c);
        hex[hex_off(d, g, t & 1, n2, j * 4 + mm)] = (__bf16)h;
      }
    }
    __syncthreads();
    // phase 7: barrier arrive (release)
    if (tid == 0) {
      __builtin_amdgcn_fence(__ATOMIC_RELEASE, "agent");
      int old = __hip_atomic_fetch_add(cntp, 1, __ATOMIC_RELAXED, __HIP_MEMORY_SCOPE_AGENT);
      if (old == WJ_ - 1) {
        __hip_atomic_store(cntp, 0, __ATOMIC_RELAXED, __HIP_MEMORY_SCOPE_AGENT);
        __builtin_amdgcn_fence(__ATOMIC_RELEASE, "agent");
        __hip_atomic_store(genp, t + 1, __ATOMIC_RELAXED, __HIP_MEMORY_SCOPE_AGENT);
      }
    }
  }
  // final emission for step Lmax-1
  wait_gen(Lmax);
  do_emis(Lmax - 1);
}

// CRF: one wave per batch; lanes = (j = l>>3 prev-state, k = l&7 next-state)
__global__ __launch_bounds__(64) void crf_pass(
    const int* __restrict__ lengths, const int* __restrict__ tags,
    const float* __restrict__ b_tag, const float* __restrict__ start_trans,
    const float* __restrict__ end_trans, const float* __restrict__ trans,
    const float* __restrict__ emisF, const float* __restrict__ emisB, float* out)
{
  int b = blockIdx.x;
  int l = threadIdx.x;
  int L = lengths[b];
  int j = l >> 3, k = l & 7;
  float trl = trans[j * 8 + k];
  float btk = b_tag[k];
  const float* eF = emisF + (size_t)b * T_ * K_;
  const float* eB = emisB + (size_t)b * T_ * K_;

  // score[state = j] replicated over k
  float score = start_trans[j] + eF[j] + eB[j] + b_tag[j];
  for (int t = 1; t < L; ++t) {
    float e = eF[t * 8 + k] + eB[t * 8 + k] + btk;
    float v = score + trl;
    float m = v;
    m = fmaxf(m, __shfl_xor(m, 8)); m = fmaxf(m, __shfl_xor(m, 16)); m = fmaxf(m, __shfl_xor(m, 32));
    float p = __expf(v - m);
    p += __shfl_xor(p, 8); p += __shfl_xor(p, 16); p += __shfl_xor(p, 32);
    float nxt = m + __logf(p) + e;     // nxt[k], replicated over j
    score = __shfl(nxt, j);            // new score[state=j]
  }
  // logZ
  float v = score + end_trans[j];
  float m = v;
  m = fmaxf(m, __shfl_xor(m, 8)); m = fmaxf(m, __shfl_xor(m, 16)); m = fmaxf(m, __shfl_xor(m, 32));
  float p = __expf(v - m);
  p += __shfl_xor(p, 8); p += __shfl_xor(p, 16); p += __shfl_xor(p, 32);
  float logZ = m + __logf(p);
  // numerator (lane-strided over t)
  const int* tg = tags + (size_t)b * T_;
  float nsum = 0.f;
  for (int t = l; t < L; t += 64) {
    int tt = tg[t];
    float e = eF[t * 8 + tt] + eB[t * 8 + tt] + b_tag[tt];
    float tr = (t > 0) ? trans[tg[t - 1] * 8 + tt] : 0.f;
    nsum += e + tr;
  }
  nsum += __shfl_xor(nsum, 1);  nsum += __shfl_xor(nsum, 2);  nsum += __shfl_xor(nsum, 4);
  nsum += __shfl_xor(nsum, 8);  nsum += __shfl_xor(nsum, 16); nsum += __shfl_xor(nsum, 32);
  if (l == 0) {
    float num = nsum + start_trans[tg[0]] + end_trans[tg[L - 1]];
    atomicAdd(out, (logZ - num) * (1.f / 32.f));
  }
}

extern "C" void kernel_launch(void* const* d_in, const int* in_sizes, int n_in,
                              void* d_out, int out_size, void* d_ws, size_t ws_size,
                              hipStream_t stream) {
  (void)in_sizes; (void)n_in; (void)out_size; (void)ws_size;
  const float* sent        = (const float*)d_in[0];
  const int*   tags        = (const int*)d_in[1];
  const int*   lengths     = (const int*)d_in[2];
  // d_in[3] = mask (unused; lengths suffice)
  const float* w_ih_f      = (const float*)d_in[4];
  const float* w_hh_f      = (const float*)d_in[5];
  const float* b_ih_f      = (const float*)d_in[6];
  const float* b_hh_f      = (const float*)d_in[7];
  const float* w_ih_b      = (const float*)d_in[8];
  const float* w_hh_b      = (const float*)d_in[9];
  const float* b_ih_b      = (const float*)d_in[10];
  const float* b_hh_b      = (const float*)d_in[11];
  const float* w_tag       = (const float*)d_in[12];
  const float* b_tag       = (const float*)d_in[13];
  const float* start_trans = (const float*)d_in[14];
  const float* end_trans   = (const float*)d_in[15];
  const float* trans       = (const float*)d_in[16];

  char* ws = (char*)d_ws;
  __bf16* hex   = (__bf16*)ws;
  int*    bars  = (int*)(ws + 65536);
  float*  emisF = (float*)(ws + (size_t)(1 << 20));
  float*  emisB = (float*)(ws + (size_t)3 * (1 << 20));

  hipMemsetAsync(d_out, 0, sizeof(float), stream);
  init_ws<<<32, 256, 0, stream>>>((int*)ws);
  lstm_pass<<<256, 256, 0, stream>>>(sent, lengths, w_ih_f, w_hh_f, b_ih_f, b_hh_f,
                                     w_ih_b, w_hh_b, b_ih_b, b_hh_b, w_tag,
                                     hex, bars, emisF, emisB);
  crf_pass<<<32, 64, 0, stream>>>(lengths, tags, b_tag, start_trans, end_trans, trans,
                                  emisF, emisB, (float*)d_out);
}